// Round 2
// baseline (294.551 us; speedup 1.0000x reference)
//
#include <hip/hip_runtime.h>
#include <stdint.h>
#include <stddef.h>

#define L_SEQ 16384
#define H_DIM 1024
#define P_DIM 512
#define N2P   1024
#define CHUNK 64
#define NCH   256   // L_SEQ / CHUNK

typedef __bf16 bf16x8 __attribute__((ext_vector_type(8)));
typedef float  f32x4  __attribute__((ext_vector_type(4)));
typedef unsigned short u16x8 __attribute__((ext_vector_type(8)));

__device__ __forceinline__ unsigned short f2bf(float x) {
  unsigned int u = __float_as_uint(x);
  u += 0x7FFFu + ((u >> 16) & 1u);   // round-to-nearest-even
  return (unsigned short)(u >> 16);
}

// ---------------------------------------------------------------------------
// Param prep: per-state lambda, lambda^CHUNK (double), coeff = (lambda-1)/Lambda
// ---------------------------------------------------------------------------
__global__ void k_prep_p(const float* __restrict__ Lre, const float* __restrict__ Lim,
                         const float* __restrict__ lstep,
                         float2* __restrict__ lam, double2* __restrict__ lamK,
                         float2* __restrict__ coeff) {
  int p = blockIdx.x * blockDim.x + threadIdx.x;
  if (p >= P_DIM) return;
  double step = exp((double)lstep[p]);
  double ar = (double)Lre[p] * step;
  double ai = (double)Lim[p] * step;
  double er = exp(ar);
  double lr = er * cos(ai), li = er * sin(ai);
  lam[p] = make_float2((float)lr, (float)li);
  double ka = (double)CHUNK * ai;
  double kr = exp((double)CHUNK * ar);
  lamK[p] = make_double2(kr * cos(ka), kr * sin(ka));
  // coeff = (lambda - 1) / Lambda
  double nr = lr - 1.0, ni = li;
  double dr = (double)Lre[p], di = (double)Lim[p];
  double den = dr * dr + di * di;
  coeff[p] = make_float2((float)((nr * dr + ni * di) / den),
                         (float)((ni * dr - nr * di) / den));
}

// Bpack: rows 0..511 = bf16(Re(B_bar)), rows 512..1023 = bf16(Im(B_bar)); (2P, H)
__global__ void k_pack_B(const float* __restrict__ Bre, const float* __restrict__ Bim,
                         const float2* __restrict__ coeff, unsigned short* __restrict__ Bp) {
  int idx = blockIdx.x * 256 + threadIdx.x;    // < P*H
  int p = idx >> 10, h = idx & 1023;
  float2 c = coeff[p];
  float br = Bre[idx], bi = Bim[idx];
  Bp[(size_t)p * H_DIM + h]            = f2bf(c.x * br - c.y * bi);
  Bp[(size_t)(P_DIM + p) * H_DIM + h]  = f2bf(c.x * bi + c.y * br);
}

// Cpack (H, 2P): cols 0..511 = bf16(C_re), cols 512..1023 = bf16(-C_im)
__global__ void k_pack_C(const float* __restrict__ Cre, const float* __restrict__ Cim,
                         unsigned short* __restrict__ Cp) {
  int idx = blockIdx.x * 256 + threadIdx.x;    // < H*2P
  int h = idx >> 10, j = idx & 1023;
  float v = (j < P_DIM) ? Cre[(size_t)h * P_DIM + j]
                        : -Cim[(size_t)h * P_DIM + (j - P_DIM)];
  Cp[idx] = f2bf(v);
}

// u (L,H) fp32 -> bf16, 8 elems/thread
__global__ void k_cast_u(const float* __restrict__ U, unsigned short* __restrict__ Ub) {
  size_t base = ((size_t)blockIdx.x * 256 + threadIdx.x) * 8;
  const float4* s = (const float4*)(U + base);
  float4 v0 = s[0], v1 = s[1];
  u16x8 o;
  o[0] = f2bf(v0.x); o[1] = f2bf(v0.y); o[2] = f2bf(v0.z); o[3] = f2bf(v0.w);
  o[4] = f2bf(v1.x); o[5] = f2bf(v1.y); o[6] = f2bf(v1.z); o[7] = f2bf(v1.w);
  *(u16x8*)(Ub + base) = o;
}

// ---------------------------------------------------------------------------
// GEMM: C(M,N) = A(M,K) @ B(N,K)^T, bf16 in / fp32 out. m97-style structure.
// 128x128 tile, BK=32, 4 waves, 4x4 mfma_f32_16x16x32_bf16 per wave.
// Grid: (M/128, N/128), blockIdx.x = M-tile (fastest). XCD-aware: with
// gridDim.x=128 ≡ 0 (mod 8), linear id ≡ m-tile (mod 8) → all N-tiles of an
// M-panel land on the SAME XCD, so each A-panel is fetched once per chip.
// FUSE=1: out = 2*acc + Dv[col]*U[row,col]
// ---------------------------------------------------------------------------
template <int FUSE>
__global__ void gemm_bt(const unsigned short* __restrict__ A,
                        const unsigned short* __restrict__ B,
                        float* __restrict__ C,
                        const float* __restrict__ U,
                        const float* __restrict__ Dv) {
  const int K = 1024, N = 1024;
  __shared__ unsigned short sA[128 * 32];
  __shared__ unsigned short sB[128 * 32];
  const int tid = threadIdx.x;
  const int wave = tid >> 6, lane = tid & 63;
  const int quad = lane >> 4, l16 = lane & 15;
  const int m0 = blockIdx.x * 128, n0 = blockIdx.y * 128;
  const int wm = (wave & 1) * 64, wn = (wave >> 1) * 64;

  f32x4 acc[4][4] = {};

  for (int kt = 0; kt < K; kt += 32) {
    __syncthreads();
#pragma unroll
    for (int r = 0; r < 2; ++r) {
      int id2 = r * 256 + tid;
      const unsigned short* ga = A + (size_t)(m0 + (id2 >> 2)) * K + kt + (id2 & 3) * 8;
      const unsigned short* gb = B + (size_t)(n0 + (id2 >> 2)) * K + kt + (id2 & 3) * 8;
      __builtin_amdgcn_global_load_lds(
          (const __attribute__((address_space(1))) unsigned int*)ga,
          (__attribute__((address_space(3))) unsigned int*)(sA + (r * 4 + wave) * 512),
          16, 0, 0);
      __builtin_amdgcn_global_load_lds(
          (const __attribute__((address_space(1))) unsigned int*)gb,
          (__attribute__((address_space(3))) unsigned int*)(sB + (r * 4 + wave) * 512),
          16, 0, 0);
    }
    __syncthreads();

    bf16x8 af[4], bfr[4];
#pragma unroll
    for (int i = 0; i < 4; ++i)
      af[i] = *(const bf16x8*)(sA + (wm + i * 16 + l16) * 32 + quad * 8);
#pragma unroll
    for (int j = 0; j < 4; ++j)
      bfr[j] = *(const bf16x8*)(sB + (wn + j * 16 + l16) * 32 + quad * 8);
#pragma unroll
    for (int i = 0; i < 4; ++i)
#pragma unroll
      for (int j = 0; j < 4; ++j)
        acc[i][j] = __builtin_amdgcn_mfma_f32_16x16x32_bf16(af[i], bfr[j], acc[i][j], 0, 0, 0);
  }

#pragma unroll
  for (int i = 0; i < 4; ++i) {
#pragma unroll
    for (int j = 0; j < 4; ++j) {
      int col = n0 + wn + j * 16 + l16;
#pragma unroll
      for (int r = 0; r < 4; ++r) {
        int row = m0 + wm + i * 16 + quad * 4 + r;
        size_t o = (size_t)row * N + col;
        float v = acc[i][j][r];
        if (FUSE) v = 2.0f * v + Dv[col] * U[o];
        C[o] = v;
      }
    }
  }
}

// ---------------------------------------------------------------------------
// Scan pass A: per-(chunk, p) local scan from zero state; store chunk sum.
// Bu layout: (L, 1024), re at col p, im at col 512+p.
// ---------------------------------------------------------------------------
__global__ void k_scanA(const float* __restrict__ Bu, const float2* __restrict__ lam,
                        float2* __restrict__ csum) {
  int idx = blockIdx.x * 256 + threadIdx.x;   // < NCH * P
  int p = idx & (P_DIM - 1), chunk = idx >> 9;
  float2 l = lam[p];
  float xr = 0.f, xi = 0.f;
  size_t base = (size_t)chunk * CHUNK * N2P + p;
#pragma unroll 8
  for (int t = 0; t < CHUNK; ++t) {
    float br = Bu[base + (size_t)t * N2P];
    float bi = Bu[base + (size_t)t * N2P + P_DIM];
    float nr = fmaf(l.x, xr, fmaf(-l.y, xi, br));
    float ni = fmaf(l.x, xi, fmaf(l.y, xr, bi));
    xr = nr; xi = ni;
  }
  csum[(size_t)chunk * P_DIM + p] = make_float2(xr, xi);
}

// Pass B: sequential scan of chunk carries per state (512 threads, double prec).
__global__ void k_scanB(const float2* __restrict__ csum, const double2* __restrict__ lamK,
                        float2* __restrict__ carry) {
  int p = blockIdx.x * 256 + threadIdx.x;
  if (p >= P_DIM) return;
  double lkr = lamK[p].x, lki = lamK[p].y;
  double cr = 0.0, ci = 0.0;
  for (int j = 0; j < NCH; ++j) {
    carry[(size_t)j * P_DIM + p] = make_float2((float)cr, (float)ci);
    float2 s = csum[(size_t)j * P_DIM + p];
    double nr = lkr * cr - lki * ci + (double)s.x;
    double ni = lkr * ci + lki * cr + (double)s.y;
    cr = nr; ci = ni;
  }
}

// Pass C: re-scan seeded with carry, write xs as bf16 (L, 2P): re col p, im col 512+p.
__global__ void k_scanC(const float* __restrict__ Bu, const float2* __restrict__ lam,
                        const float2* __restrict__ carry, unsigned short* __restrict__ xs) {
  int idx = blockIdx.x * 256 + threadIdx.x;
  int p = idx & (P_DIM - 1), chunk = idx >> 9;
  float2 l = lam[p];
  float2 c0 = carry[(size_t)chunk * P_DIM + p];
  float xr = c0.x, xi = c0.y;
  size_t base = (size_t)chunk * CHUNK * N2P + p;
#pragma unroll 8
  for (int t = 0; t < CHUNK; ++t) {
    float br = Bu[base + (size_t)t * N2P];
    float bi = Bu[base + (size_t)t * N2P + P_DIM];
    float nr = fmaf(l.x, xr, fmaf(-l.y, xi, br));
    float ni = fmaf(l.x, xi, fmaf(l.y, xr, bi));
    xr = nr; xi = ni;
    xs[base + (size_t)t * N2P]         = f2bf(xr);
    xs[base + (size_t)t * N2P + P_DIM] = f2bf(xi);
  }
}

// ---------------------------------------------------------------------------
extern "C" void kernel_launch(void* const* d_in, const int* in_sizes, int n_in,
                              void* d_out, int out_size, void* d_ws, size_t ws_size,
                              hipStream_t stream) {
  const float* U    = (const float*)d_in[0];
  const float* Lre  = (const float*)d_in[1];
  const float* Lim  = (const float*)d_in[2];
  const float* Bre  = (const float*)d_in[3];
  const float* Bim  = (const float*)d_in[4];
  const float* Cre  = (const float*)d_in[5];
  const float* Cim  = (const float*)d_in[6];
  const float* Dv   = (const float*)d_in[7];
  const float* lstp = (const float*)d_in[8];
  float* out = (float*)d_out;

  size_t off = 0;
  char* ws = (char*)d_ws;
  auto give = [&](size_t bytes) -> void* {
    void* p = ws + off;
    off += (bytes + 255) & ~(size_t)255;
    return p;
  };

  // u_bf is dead after GEMM1; reuse its buffer for xs (written by scanC).
  unsigned short* ubf_xs = (unsigned short*)give((size_t)L_SEQ * H_DIM * 2);  // 33.5 MB
  unsigned short* Bp     = (unsigned short*)give((size_t)N2P * H_DIM * 2);    //  2 MB
  unsigned short* Cp     = (unsigned short*)give((size_t)H_DIM * N2P * 2);    //  2 MB
  float*          Bu     = (float*)give((size_t)L_SEQ * N2P * 4);             // 67 MB
  float2*         lam    = (float2*)give(P_DIM * sizeof(float2));
  double2*        lamK   = (double2*)give(P_DIM * sizeof(double2));
  float2*         coeff  = (float2*)give(P_DIM * sizeof(float2));
  float2*         csum   = (float2*)give((size_t)NCH * P_DIM * sizeof(float2));
  float2*         carry  = (float2*)give((size_t)NCH * P_DIM * sizeof(float2));

  k_prep_p<<<2, 256, 0, stream>>>(Lre, Lim, lstp, lam, lamK, coeff);
  k_pack_B<<<(P_DIM * H_DIM) / 256, 256, 0, stream>>>(Bre, Bim, coeff, Bp);
  k_pack_C<<<(H_DIM * N2P) / 256, 256, 0, stream>>>(Cre, Cim, Cp);
  k_cast_u<<<(L_SEQ * H_DIM) / (256 * 8), 256, 0, stream>>>(U, ubf_xs);

  gemm_bt<0><<<dim3(L_SEQ / 128, N2P / 128), 256, 0, stream>>>(ubf_xs, Bp, Bu, nullptr, nullptr);

  k_scanA<<<(NCH * P_DIM) / 256, 256, 0, stream>>>(Bu, lam, csum);
  k_scanB<<<2, 256, 0, stream>>>(csum, lamK, carry);
  k_scanC<<<(NCH * P_DIM) / 256, 256, 0, stream>>>(Bu, lam, carry, ubf_xs);

  gemm_bt<1><<<dim3(L_SEQ / 128, N2P / 128), 256, 0, stream>>>(ubf_xs, Cp, out, U, Dv);
}

// Round 3
// 276.039 us; speedup vs baseline: 1.0671x; 1.0671x over previous
//
#include <hip/hip_runtime.h>
#include <stdint.h>
#include <stddef.h>

#define L_SEQ 16384
#define H_DIM 1024
#define P_DIM 512
#define N2P   1024
#define CHUNK 64
#define NCH   256   // L_SEQ / CHUNK

typedef __bf16 bf16x8 __attribute__((ext_vector_type(8)));
typedef float  f32x4  __attribute__((ext_vector_type(4)));
typedef unsigned short u16x8 __attribute__((ext_vector_type(8)));

__device__ __forceinline__ unsigned short f2bf(float x) {
  unsigned int u = __float_as_uint(x);
  u += 0x7FFFu + ((u >> 16) & 1u);   // round-to-nearest-even
  return (unsigned short)(u >> 16);
}
__device__ __forceinline__ float bf2f(unsigned short x) {
  return __uint_as_float((unsigned int)x << 16);
}

// ---------------------------------------------------------------------------
// Param prep
// ---------------------------------------------------------------------------
__global__ void k_prep_p(const float* __restrict__ Lre, const float* __restrict__ Lim,
                         const float* __restrict__ lstep,
                         float2* __restrict__ lam, double2* __restrict__ lamK,
                         float2* __restrict__ coeff) {
  int p = blockIdx.x * blockDim.x + threadIdx.x;
  if (p >= P_DIM) return;
  double step = exp((double)lstep[p]);
  double ar = (double)Lre[p] * step;
  double ai = (double)Lim[p] * step;
  double er = exp(ar);
  double lr = er * cos(ai), li = er * sin(ai);
  lam[p] = make_float2((float)lr, (float)li);
  double ka = (double)CHUNK * ai;
  double kr = exp((double)CHUNK * ar);
  lamK[p] = make_double2(kr * cos(ka), kr * sin(ka));
  double nr = lr - 1.0, ni = li;
  double dr = (double)Lre[p], di = (double)Lim[p];
  double den = dr * dr + di * di;
  coeff[p] = make_float2((float)((nr * dr + ni * di) / den),
                         (float)((ni * dr - nr * di) / den));
}

// Bpack (2P, H): row 2p = bf16(Re(B_bar)[p]), row 2p+1 = bf16(Im(B_bar)[p])
__global__ void k_pack_B(const float* __restrict__ Bre, const float* __restrict__ Bim,
                         const float2* __restrict__ coeff, unsigned short* __restrict__ Bp) {
  int idx = blockIdx.x * 256 + threadIdx.x;    // < P*H
  int p = idx >> 10, h = idx & 1023;
  float2 c = coeff[p];
  float br = Bre[idx], bi = Bim[idx];
  Bp[(size_t)(2 * p) * H_DIM + h]     = f2bf(c.x * br - c.y * bi);
  Bp[(size_t)(2 * p + 1) * H_DIM + h] = f2bf(c.x * bi + c.y * br);
}

// Cpack (H, 2P): col 2p = bf16(C_re[h][p]), col 2p+1 = bf16(-C_im[h][p])
__global__ void k_pack_C(const float* __restrict__ Cre, const float* __restrict__ Cim,
                         unsigned short* __restrict__ Cp) {
  int idx = blockIdx.x * 256 + threadIdx.x;    // < H*2P
  int h = idx >> 10, j = idx & 1023;
  int p = j >> 1;
  float v = (j & 1) ? -Cim[(size_t)h * P_DIM + p] : Cre[(size_t)h * P_DIM + p];
  Cp[idx] = f2bf(v);
}

// u (L,H) fp32 -> bf16, 8 elems/thread
__global__ void k_cast_u(const float* __restrict__ U, unsigned short* __restrict__ Ub) {
  size_t base = ((size_t)blockIdx.x * 256 + threadIdx.x) * 8;
  const float4* s = (const float4*)(U + base);
  float4 v0 = s[0], v1 = s[1];
  u16x8 o;
  o[0] = f2bf(v0.x); o[1] = f2bf(v0.y); o[2] = f2bf(v0.z); o[3] = f2bf(v0.w);
  o[4] = f2bf(v1.x); o[5] = f2bf(v1.y); o[6] = f2bf(v1.z); o[7] = f2bf(v1.w);
  *(u16x8*)(Ub + base) = o;
}

// ---------------------------------------------------------------------------
// GEMM: out(M,N) = A(M,K) @ B(N,K)^T, bf16 in. 128x128 tile, BK=64, 4 waves,
// 4x4 mfma_f32_16x16x32_bf16 per wave per k-half. Grid (M/128, N/128),
// blockIdx.x fastest => all N-tiles of an M-panel on same XCD (A fetched once).
// OUT=0: bf16 store. OUT=1: fp32 store, fused 2*acc + Dv[col]*bf2f(Ub[row,col]).
// ---------------------------------------------------------------------------
template <int OUT>
__global__ void gemm_bt(const unsigned short* __restrict__ A,
                        const unsigned short* __restrict__ B,
                        void* __restrict__ Cout,
                        const unsigned short* __restrict__ Ub,
                        const float* __restrict__ Dv) {
  const int K = 1024, N = 1024;
  __shared__ unsigned short sA[128 * 64];
  __shared__ unsigned short sB[128 * 64];
  const int tid = threadIdx.x;
  const int wave = tid >> 6, lane = tid & 63;
  const int quad = lane >> 4, l16 = lane & 15;
  const int m0 = blockIdx.x * 128, n0 = blockIdx.y * 128;
  const int wm = (wave & 1) * 64, wn = (wave >> 1) * 64;

  f32x4 acc[4][4] = {};

  for (int kt = 0; kt < K; kt += 64) {
    __syncthreads();
#pragma unroll
    for (int r = 0; r < 4; ++r) {
      int id2 = r * 256 + tid;                 // 0..1023: row=id2>>3, col8=(id2&7)*8
      const unsigned short* ga = A + (size_t)(m0 + (id2 >> 3)) * K + kt + (id2 & 7) * 8;
      const unsigned short* gb = B + (size_t)(n0 + (id2 >> 3)) * K + kt + (id2 & 7) * 8;
      __builtin_amdgcn_global_load_lds(
          (const __attribute__((address_space(1))) unsigned int*)ga,
          (__attribute__((address_space(3))) unsigned int*)(sA + (r * 256 + wave * 64) * 8),
          16, 0, 0);
      __builtin_amdgcn_global_load_lds(
          (const __attribute__((address_space(1))) unsigned int*)gb,
          (__attribute__((address_space(3))) unsigned int*)(sB + (r * 256 + wave * 64) * 8),
          16, 0, 0);
    }
    __syncthreads();

#pragma unroll
    for (int h = 0; h < 2; ++h) {
      bf16x8 af[4], bfr[4];
#pragma unroll
      for (int i = 0; i < 4; ++i)
        af[i] = *(const bf16x8*)(sA + (wm + i * 16 + l16) * 64 + h * 32 + quad * 8);
#pragma unroll
      for (int j = 0; j < 4; ++j)
        bfr[j] = *(const bf16x8*)(sB + (wn + j * 16 + l16) * 64 + h * 32 + quad * 8);
#pragma unroll
      for (int i = 0; i < 4; ++i)
#pragma unroll
        for (int j = 0; j < 4; ++j)
          acc[i][j] = __builtin_amdgcn_mfma_f32_16x16x32_bf16(af[i], bfr[j], acc[i][j], 0, 0, 0);
    }
  }

#pragma unroll
  for (int i = 0; i < 4; ++i) {
#pragma unroll
    for (int j = 0; j < 4; ++j) {
      int col = n0 + wn + j * 16 + l16;
#pragma unroll
      for (int r = 0; r < 4; ++r) {
        int row = m0 + wm + i * 16 + quad * 4 + r;
        size_t o = (size_t)row * N + col;
        float v = acc[i][j][r];
        if (OUT) {
          float u = bf2f(Ub[o]);
          ((float*)Cout)[o] = 2.0f * v + Dv[col] * u;
        } else {
          ((unsigned short*)Cout)[o] = f2bf(v);
        }
      }
    }
  }
}

// ---------------------------------------------------------------------------
// Scan pass A: per-(chunk,p) local scan from zero; store chunk sum.
// Bu bf16 (L, 2P) interleaved: col 2p = re, 2p+1 = im -> one 4B load per step.
// ---------------------------------------------------------------------------
__global__ void k_scanA(const unsigned short* __restrict__ Bu, const float2* __restrict__ lam,
                        float2* __restrict__ csum) {
  int idx = blockIdx.x * 256 + threadIdx.x;   // < NCH * P
  int p = idx & (P_DIM - 1), chunk = idx >> 9;
  float2 l = lam[p];
  float xr = 0.f, xi = 0.f;
  const unsigned int* base = (const unsigned int*)(Bu + (size_t)chunk * CHUNK * N2P + 2 * p);
#pragma unroll 8
  for (int t = 0; t < CHUNK; ++t) {
    unsigned int v = base[(size_t)t * (N2P / 2)];
    float br = bf2f((unsigned short)(v & 0xffffu));
    float bi = bf2f((unsigned short)(v >> 16));
    float nr = fmaf(l.x, xr, fmaf(-l.y, xi, br));
    float ni = fmaf(l.x, xi, fmaf(l.y, xr, bi));
    xr = nr; xi = ni;
  }
  csum[(size_t)chunk * P_DIM + p] = make_float2(xr, xi);
}

// Pass B: sequential carry scan per state (double precision).
__global__ void k_scanB(const float2* __restrict__ csum, const double2* __restrict__ lamK,
                        float2* __restrict__ carry) {
  int p = blockIdx.x * 256 + threadIdx.x;
  if (p >= P_DIM) return;
  double lkr = lamK[p].x, lki = lamK[p].y;
  double cr = 0.0, ci = 0.0;
  for (int j = 0; j < NCH; ++j) {
    carry[(size_t)j * P_DIM + p] = make_float2((float)cr, (float)ci);
    float2 s = csum[(size_t)j * P_DIM + p];
    double nr = lkr * cr - lki * ci + (double)s.x;
    double ni = lkr * ci + lki * cr + (double)s.y;
    cr = nr; ci = ni;
  }
}

// Pass C: re-scan seeded with carry, write xs bf16 (L, 2P) interleaved.
__global__ void k_scanC(const unsigned short* __restrict__ Bu, const float2* __restrict__ lam,
                        const float2* __restrict__ carry, unsigned short* __restrict__ xs) {
  int idx = blockIdx.x * 256 + threadIdx.x;
  int p = idx & (P_DIM - 1), chunk = idx >> 9;
  float2 l = lam[p];
  float2 c0 = carry[(size_t)chunk * P_DIM + p];
  float xr = c0.x, xi = c0.y;
  const unsigned int* base = (const unsigned int*)(Bu + (size_t)chunk * CHUNK * N2P + 2 * p);
  unsigned int* obase = (unsigned int*)(xs + (size_t)chunk * CHUNK * N2P + 2 * p);
#pragma unroll 8
  for (int t = 0; t < CHUNK; ++t) {
    unsigned int v = base[(size_t)t * (N2P / 2)];
    float br = bf2f((unsigned short)(v & 0xffffu));
    float bi = bf2f((unsigned short)(v >> 16));
    float nr = fmaf(l.x, xr, fmaf(-l.y, xi, br));
    float ni = fmaf(l.x, xi, fmaf(l.y, xr, bi));
    xr = nr; xi = ni;
    obase[(size_t)t * (N2P / 2)] = (unsigned int)f2bf(xr) | ((unsigned int)f2bf(xi) << 16);
  }
}

// ---------------------------------------------------------------------------
extern "C" void kernel_launch(void* const* d_in, const int* in_sizes, int n_in,
                              void* d_out, int out_size, void* d_ws, size_t ws_size,
                              hipStream_t stream) {
  const float* U    = (const float*)d_in[0];
  const float* Lre  = (const float*)d_in[1];
  const float* Lim  = (const float*)d_in[2];
  const float* Bre  = (const float*)d_in[3];
  const float* Bim  = (const float*)d_in[4];
  const float* Cre  = (const float*)d_in[5];
  const float* Cim  = (const float*)d_in[6];
  const float* Dv   = (const float*)d_in[7];
  const float* lstp = (const float*)d_in[8];
  float* out = (float*)d_out;

  size_t off = 0;
  char* ws = (char*)d_ws;
  auto give = [&](size_t bytes) -> void* {
    void* p = ws + off;
    off += (bytes + 255) & ~(size_t)255;
    return p;
  };

  unsigned short* ubf  = (unsigned short*)give((size_t)L_SEQ * H_DIM * 2);  // 33.5 MB (kept for GEMM2 fuse)
  unsigned short* Bp   = (unsigned short*)give((size_t)N2P * H_DIM * 2);    //  2 MB
  unsigned short* Cp   = (unsigned short*)give((size_t)H_DIM * N2P * 2);    //  2 MB
  unsigned short* Bu   = (unsigned short*)give((size_t)L_SEQ * N2P * 2);    // 33.5 MB (bf16)
  unsigned short* xs   = (unsigned short*)give((size_t)L_SEQ * N2P * 2);    // 33.5 MB (bf16)
  float2*         lam  = (float2*)give(P_DIM * sizeof(float2));
  double2*        lamK = (double2*)give(P_DIM * sizeof(double2));
  float2*         coef = (float2*)give(P_DIM * sizeof(float2));
  float2*         csum = (float2*)give((size_t)NCH * P_DIM * sizeof(float2));
  float2*         carry= (float2*)give((size_t)NCH * P_DIM * sizeof(float2));

  k_prep_p<<<2, 256, 0, stream>>>(Lre, Lim, lstp, lam, lamK, coef);
  k_pack_B<<<(P_DIM * H_DIM) / 256, 256, 0, stream>>>(Bre, Bim, coef, Bp);
  k_pack_C<<<(H_DIM * N2P) / 256, 256, 0, stream>>>(Cre, Cim, Cp);
  k_cast_u<<<(L_SEQ * H_DIM) / (256 * 8), 256, 0, stream>>>(U, ubf);

  gemm_bt<0><<<dim3(L_SEQ / 128, N2P / 128), 256, 0, stream>>>(ubf, Bp, Bu, nullptr, nullptr);

  k_scanA<<<(NCH * P_DIM) / 256, 256, 0, stream>>>(Bu, lam, csum);
  k_scanB<<<2, 256, 0, stream>>>(csum, lamK, carry);
  k_scanC<<<(NCH * P_DIM) / 256, 256, 0, stream>>>(Bu, lam, carry, xs);

  gemm_bt<1><<<dim3(L_SEQ / 128, N2P / 128), 256, 0, stream>>>(xs, Cp, out, ubf, Dv);
}

// Round 4
// 270.571 us; speedup vs baseline: 1.0886x; 1.0202x over previous
//
#include <hip/hip_runtime.h>
#include <stdint.h>
#include <stddef.h>

#define L_SEQ 16384
#define H_DIM 1024
#define P_DIM 512
#define N2P   1024
#define CHUNK 64
#define NCH   256   // L_SEQ / CHUNK

// merged pack-kernel block ranges
#define NB_U 8192   // L*H/(256*8)
#define NB_B 2048   // P*H/256
#define NB_C 4096   // H*2P/256
#define NB_T 2      // lambda tables

typedef __bf16 bf16x8 __attribute__((ext_vector_type(8)));
typedef float  f32x4  __attribute__((ext_vector_type(4)));
typedef unsigned short u16x8 __attribute__((ext_vector_type(8)));

__device__ __forceinline__ unsigned short f2bf(float x) {
  unsigned int u = __float_as_uint(x);
  u += 0x7FFFu + ((u >> 16) & 1u);   // round-to-nearest-even
  return (unsigned short)(u >> 16);
}
__device__ __forceinline__ float bf2f(unsigned short x) {
  return __uint_as_float((unsigned int)x << 16);
}

// ---------------------------------------------------------------------------
// Merged pack: [0,NB_U) u->bf16 cast; [NB_U,+NB_B) B_bar pack; then C pack;
// then lambda tables. All branches are block-uniform.
// Bp (2P,H): row 2p=Re, 2p+1=Im.  Cp (H,2P): col 2p=C_re, 2p+1=-C_im.
// ---------------------------------------------------------------------------
__global__ void k_pack_all(const float* __restrict__ U, unsigned short* __restrict__ Ub,
                           const float* __restrict__ Bre, const float* __restrict__ Bim,
                           unsigned short* __restrict__ Bp,
                           const float* __restrict__ Cre, const float* __restrict__ Cim,
                           unsigned short* __restrict__ Cp,
                           const float* __restrict__ Lre, const float* __restrict__ Lim,
                           const float* __restrict__ lstep,
                           float2* __restrict__ lam, float2* __restrict__ lamK) {
  int bid = blockIdx.x, tid = threadIdx.x;
  if (bid < NB_U) {
    size_t base = ((size_t)bid * 256 + tid) * 8;
    const float4* s = (const float4*)(U + base);
    float4 v0 = s[0], v1 = s[1];
    u16x8 o;
    o[0] = f2bf(v0.x); o[1] = f2bf(v0.y); o[2] = f2bf(v0.z); o[3] = f2bf(v0.w);
    o[4] = f2bf(v1.x); o[5] = f2bf(v1.y); o[6] = f2bf(v1.z); o[7] = f2bf(v1.w);
    *(u16x8*)(Ub + base) = o;
  } else if (bid < NB_U + NB_B) {
    int idx = (bid - NB_U) * 256 + tid;        // < P*H
    int p = idx >> 10, h = idx & 1023;
    // coeff = (lambda - 1) / Lambda, double precision per thread
    double step = exp((double)lstep[p]);
    double ar = (double)Lre[p] * step, ai = (double)Lim[p] * step;
    double er = exp(ar);
    double lr = er * cos(ai), li = er * sin(ai);
    double nr = lr - 1.0, ni = li;
    double dr = (double)Lre[p], di = (double)Lim[p];
    double den = dr * dr + di * di;
    float cx = (float)((nr * dr + ni * di) / den);
    float cy = (float)((ni * dr - nr * di) / den);
    float br = Bre[idx], bi = Bim[idx];
    Bp[(size_t)(2 * p) * H_DIM + h]     = f2bf(cx * br - cy * bi);
    Bp[(size_t)(2 * p + 1) * H_DIM + h] = f2bf(cx * bi + cy * br);
  } else if (bid < NB_U + NB_B + NB_C) {
    int idx = (bid - NB_U - NB_B) * 256 + tid; // < H*2P
    int h = idx >> 10, j = idx & 1023;
    int p = j >> 1;
    float v = (j & 1) ? -Cim[(size_t)h * P_DIM + p] : Cre[(size_t)h * P_DIM + p];
    Cp[idx] = f2bf(v);
  } else {
    int p = (bid - NB_U - NB_B - NB_C) * 256 + tid;
    if (p < P_DIM) {
      double step = exp((double)lstep[p]);
      double ar = (double)Lre[p] * step, ai = (double)Lim[p] * step;
      double er = exp(ar);
      lam[p] = make_float2((float)(er * cos(ai)), (float)(er * sin(ai)));
      double ka = (double)CHUNK * ai, kr = exp((double)CHUNK * ar);
      lamK[p] = make_float2((float)(kr * cos(ka)), (float)(kr * sin(ka)));
    }
  }
}

// ---------------------------------------------------------------------------
// GEMM: out(M,N) = A(M,K) @ B(N,K)^T, bf16 in. 128x128 tile, BK=64, 4 waves,
// 4x4 mfma_f32_16x16x32_bf16. Grid (M/128, N/128), blockIdx.x fastest =>
// all N-tiles of an M-panel on the same XCD (A-panel fetched once per chip).
// LDS XOR swizzle: element-group (row, j8) is stored at slot row*8 +
// (j8 ^ (row&7)). Staging permutes the GLOBAL source address per lane
// (global_load_lds dest must stay base+lane*16); fragment reads apply the
// same XOR. Each 16-lane quad-group then spreads across all 32 banks
// (2 lanes/bank = free, m136) instead of 16-way aliasing 4 banks.
// OUT=0: bf16 store. OUT=1: fp32 store, fused 2*acc + Dv[col]*bf2f(Ub).
// ---------------------------------------------------------------------------
template <int OUT>
__global__ void gemm_bt(const unsigned short* __restrict__ A,
                        const unsigned short* __restrict__ B,
                        void* __restrict__ Cout,
                        const unsigned short* __restrict__ Ub,
                        const float* __restrict__ Dv) {
  const int K = 1024, N = 1024;
  __shared__ unsigned short sA[128 * 64];
  __shared__ unsigned short sB[128 * 64];
  const int tid = threadIdx.x;
  const int wave = tid >> 6, lane = tid & 63;
  const int quad = lane >> 4, l16 = lane & 15;
  const int m0 = blockIdx.x * 128, n0 = blockIdx.y * 128;
  const int wm = (wave & 1) * 64, wn = (wave >> 1) * 64;

  f32x4 acc[4][4] = {};

  for (int kt = 0; kt < K; kt += 64) {
    __syncthreads();
#pragma unroll
    for (int r = 0; r < 4; ++r) {
      int s = r * 256 + tid;                   // LDS slot = staging index
      int row = s >> 3;
      int j8 = (s & 7) ^ (row & 7);            // swizzled global column-group
      const unsigned short* ga = A + (size_t)(m0 + row) * K + kt + j8 * 8;
      const unsigned short* gb = B + (size_t)(n0 + row) * K + kt + j8 * 8;
      __builtin_amdgcn_global_load_lds(
          (const __attribute__((address_space(1))) unsigned int*)ga,
          (__attribute__((address_space(3))) unsigned int*)(sA + (r * 256 + wave * 64) * 8),
          16, 0, 0);
      __builtin_amdgcn_global_load_lds(
          (const __attribute__((address_space(1))) unsigned int*)gb,
          (__attribute__((address_space(3))) unsigned int*)(sB + (r * 256 + wave * 64) * 8),
          16, 0, 0);
    }
    __syncthreads();

#pragma unroll
    for (int h = 0; h < 2; ++h) {
      bf16x8 af[4], bfr[4];
#pragma unroll
      for (int i = 0; i < 4; ++i) {
        int ra = wm + i * 16 + l16;
        af[i] = *(const bf16x8*)(sA + ra * 64 + (((h << 2) + quad) ^ (ra & 7)) * 8);
      }
#pragma unroll
      for (int j = 0; j < 4; ++j) {
        int rb = wn + j * 16 + l16;
        bfr[j] = *(const bf16x8*)(sB + rb * 64 + (((h << 2) + quad) ^ (rb & 7)) * 8);
      }
#pragma unroll
      for (int i = 0; i < 4; ++i)
#pragma unroll
        for (int j = 0; j < 4; ++j)
          acc[i][j] = __builtin_amdgcn_mfma_f32_16x16x32_bf16(af[i], bfr[j], acc[i][j], 0, 0, 0);
    }
  }

#pragma unroll
  for (int i = 0; i < 4; ++i) {
#pragma unroll
    for (int j = 0; j < 4; ++j) {
      int col = n0 + wn + j * 16 + l16;
#pragma unroll
      for (int r = 0; r < 4; ++r) {
        int row = m0 + wm + i * 16 + quad * 4 + r;
        size_t o = (size_t)row * N + col;
        float v = acc[i][j][r];
        if (OUT) {
          float u = bf2f(Ub[o]);
          ((float*)Cout)[o] = 2.0f * v + Dv[col] * u;
        } else {
          ((unsigned short*)Cout)[o] = f2bf(v);
        }
      }
    }
  }
}

// ---------------------------------------------------------------------------
// Scan pass A: per-(chunk,p) local scan from zero; store chunk sum.
// Bu bf16 (L, 2P) interleaved: col 2p = re, 2p+1 = im -> one 4B load per step.
// csum layout (chunk, p) float2.
// ---------------------------------------------------------------------------
__global__ void k_scanA(const unsigned short* __restrict__ Bu, const float2* __restrict__ lam,
                        float2* __restrict__ csum) {
  int idx = blockIdx.x * 256 + threadIdx.x;   // < NCH * P
  int p = idx & (P_DIM - 1), chunk = idx >> 9;
  float2 l = lam[p];
  float xr = 0.f, xi = 0.f;
  const unsigned int* base = (const unsigned int*)(Bu + (size_t)chunk * CHUNK * N2P + 2 * p);
#pragma unroll 8
  for (int t = 0; t < CHUNK; ++t) {
    unsigned int v = base[(size_t)t * (N2P / 2)];
    float br = bf2f((unsigned short)(v & 0xffffu));
    float bi = bf2f((unsigned short)(v >> 16));
    float nr = fmaf(l.x, xr, fmaf(-l.y, xi, br));
    float ni = fmaf(l.x, xi, fmaf(l.y, xr, bi));
    xr = nr; xi = ni;
  }
  csum[(size_t)chunk * P_DIM + p] = make_float2(xr, xi);
}

// ---------------------------------------------------------------------------
// Scan pass C with Horner lookback (replaces the serial scanB kernel):
// carry(chunk,p) = sum_{j<chunk} lamK^(chunk-1-j) * csum[j][p], evaluated as
// c = lamK*c + csum[j] for j = 0..chunk-1 (loads are independent -> pipelined,
// csum is 1 MB -> L2-resident). Then re-scan seeded with carry, write xs bf16.
// ---------------------------------------------------------------------------
__global__ void k_scanC(const unsigned short* __restrict__ Bu, const float2* __restrict__ lam,
                        const float2* __restrict__ lamK, const float2* __restrict__ csum,
                        unsigned short* __restrict__ xs) {
  int idx = blockIdx.x * 256 + threadIdx.x;
  int p = idx & (P_DIM - 1), chunk = idx >> 9;
  float2 l = lam[p];
  float2 lk = lamK[p];
  float cr = 0.f, ci = 0.f;
#pragma unroll 4
  for (int j = 0; j < chunk; ++j) {
    float2 s = csum[(size_t)j * P_DIM + p];
    float nr = fmaf(lk.x, cr, fmaf(-lk.y, ci, s.x));
    float ni = fmaf(lk.x, ci, fmaf(lk.y, cr, s.y));
    cr = nr; ci = ni;
  }
  float xr = cr, xi = ci;
  const unsigned int* base = (const unsigned int*)(Bu + (size_t)chunk * CHUNK * N2P + 2 * p);
  unsigned int* obase = (unsigned int*)(xs + (size_t)chunk * CHUNK * N2P + 2 * p);
#pragma unroll 8
  for (int t = 0; t < CHUNK; ++t) {
    unsigned int v = base[(size_t)t * (N2P / 2)];
    float br = bf2f((unsigned short)(v & 0xffffu));
    float bi = bf2f((unsigned short)(v >> 16));
    float nr = fmaf(l.x, xr, fmaf(-l.y, xi, br));
    float ni = fmaf(l.x, xi, fmaf(l.y, xr, bi));
    xr = nr; xi = ni;
    obase[(size_t)t * (N2P / 2)] = (unsigned int)f2bf(xr) | ((unsigned int)f2bf(xi) << 16);
  }
}

// ---------------------------------------------------------------------------
extern "C" void kernel_launch(void* const* d_in, const int* in_sizes, int n_in,
                              void* d_out, int out_size, void* d_ws, size_t ws_size,
                              hipStream_t stream) {
  const float* U    = (const float*)d_in[0];
  const float* Lre  = (const float*)d_in[1];
  const float* Lim  = (const float*)d_in[2];
  const float* Bre  = (const float*)d_in[3];
  const float* Bim  = (const float*)d_in[4];
  const float* Cre  = (const float*)d_in[5];
  const float* Cim  = (const float*)d_in[6];
  const float* Dv   = (const float*)d_in[7];
  const float* lstp = (const float*)d_in[8];
  float* out = (float*)d_out;

  size_t off = 0;
  char* ws = (char*)d_ws;
  auto give = [&](size_t bytes) -> void* {
    void* p = ws + off;
    off += (bytes + 255) & ~(size_t)255;
    return p;
  };

  unsigned short* ubf  = (unsigned short*)give((size_t)L_SEQ * H_DIM * 2);  // 33.5 MB
  unsigned short* Bp   = (unsigned short*)give((size_t)N2P * H_DIM * 2);    //  2 MB
  unsigned short* Cp   = (unsigned short*)give((size_t)H_DIM * N2P * 2);    //  2 MB
  unsigned short* Bu   = (unsigned short*)give((size_t)L_SEQ * N2P * 2);    // 33.5 MB
  unsigned short* xs   = (unsigned short*)give((size_t)L_SEQ * N2P * 2);    // 33.5 MB
  float2*         lam  = (float2*)give(P_DIM * sizeof(float2));
  float2*         lamK = (float2*)give(P_DIM * sizeof(float2));
  float2*         csum = (float2*)give((size_t)NCH * P_DIM * sizeof(float2));

  k_pack_all<<<NB_U + NB_B + NB_C + NB_T, 256, 0, stream>>>(
      U, ubf, Bre, Bim, Bp, Cre, Cim, Cp, Lre, Lim, lstp, lam, lamK);

  gemm_bt<0><<<dim3(L_SEQ / 128, N2P / 128), 256, 0, stream>>>(ubf, Bp, Bu, nullptr, nullptr);

  k_scanA<<<(NCH * P_DIM) / 256, 256, 0, stream>>>(Bu, lam, csum);
  k_scanC<<<(NCH * P_DIM) / 256, 256, 0, stream>>>(Bu, lam, lamK, csum, xs);

  gemm_bt<1><<<dim3(L_SEQ / 128, N2P / 128), 256, 0, stream>>>(xs, Cp, out, ubf, Dv);
}

// Round 5
// 265.135 us; speedup vs baseline: 1.1109x; 1.0205x over previous
//
#include <hip/hip_runtime.h>
#include <stdint.h>
#include <stddef.h>

#define L_SEQ 16384
#define H_DIM 1024
#define P_DIM 512
#define N2P   1024
#define CHUNK 64
#define NCH   256   // L_SEQ / CHUNK

// merged pack-kernel block ranges
#define NB_U 8192   // L*H/(256*8)
#define NB_B 2048   // P*H/256
#define NB_C 4096   // H*2P/256
#define NB_T 2      // lambda tables

typedef __bf16 bf16x8 __attribute__((ext_vector_type(8)));
typedef float  f32x4  __attribute__((ext_vector_type(4)));
typedef unsigned short u16x8 __attribute__((ext_vector_type(8)));
typedef unsigned int   u32x4 __attribute__((ext_vector_type(4)));

__device__ __forceinline__ unsigned short f2bf(float x) {
  unsigned int u = __float_as_uint(x);
  u += 0x7FFFu + ((u >> 16) & 1u);   // round-to-nearest-even
  return (unsigned short)(u >> 16);
}
__device__ __forceinline__ float bf2f(unsigned short x) {
  return __uint_as_float((unsigned int)x << 16);
}

// ---------------------------------------------------------------------------
// Merged pack: [0,NB_U) u->bf16 cast; [NB_U,+NB_B) B_bar pack; then C pack;
// then lambda tables. All branches are block-uniform.
// Bp (2P,H): row 2p=Re, 2p+1=Im.  Cp (H,2P): col 2p=C_re, 2p+1=-C_im.
// ---------------------------------------------------------------------------
__global__ void k_pack_all(const float* __restrict__ U, unsigned short* __restrict__ Ub,
                           const float* __restrict__ Bre, const float* __restrict__ Bim,
                           unsigned short* __restrict__ Bp,
                           const float* __restrict__ Cre, const float* __restrict__ Cim,
                           unsigned short* __restrict__ Cp,
                           const float* __restrict__ Lre, const float* __restrict__ Lim,
                           const float* __restrict__ lstep,
                           float2* __restrict__ lam, float2* __restrict__ lamK) {
  int bid = blockIdx.x, tid = threadIdx.x;
  if (bid < NB_U) {
    size_t base = ((size_t)bid * 256 + tid) * 8;
    const float4* s = (const float4*)(U + base);
    float4 v0 = s[0], v1 = s[1];
    u16x8 o;
    o[0] = f2bf(v0.x); o[1] = f2bf(v0.y); o[2] = f2bf(v0.z); o[3] = f2bf(v0.w);
    o[4] = f2bf(v1.x); o[5] = f2bf(v1.y); o[6] = f2bf(v1.z); o[7] = f2bf(v1.w);
    *(u16x8*)(Ub + base) = o;
  } else if (bid < NB_U + NB_B) {
    int idx = (bid - NB_U) * 256 + tid;        // < P*H
    int p = idx >> 10, h = idx & 1023;
    // coeff = (lambda - 1) / Lambda, double precision per thread
    double step = exp((double)lstep[p]);
    double ar = (double)Lre[p] * step, ai = (double)Lim[p] * step;
    double er = exp(ar);
    double lr = er * cos(ai), li = er * sin(ai);
    double nr = lr - 1.0, ni = li;
    double dr = (double)Lre[p], di = (double)Lim[p];
    double den = dr * dr + di * di;
    float cx = (float)((nr * dr + ni * di) / den);
    float cy = (float)((ni * dr - nr * di) / den);
    float br = Bre[idx], bi = Bim[idx];
    Bp[(size_t)(2 * p) * H_DIM + h]     = f2bf(cx * br - cy * bi);
    Bp[(size_t)(2 * p + 1) * H_DIM + h] = f2bf(cx * bi + cy * br);
  } else if (bid < NB_U + NB_B + NB_C) {
    int idx = (bid - NB_U - NB_B) * 256 + tid; // < H*2P
    int h = idx >> 10, j = idx & 1023;
    int p = j >> 1;
    float v = (j & 1) ? -Cim[(size_t)h * P_DIM + p] : Cre[(size_t)h * P_DIM + p];
    Cp[idx] = f2bf(v);
  } else {
    int p = (bid - NB_U - NB_B - NB_C) * 256 + tid;
    if (p < P_DIM) {
      double step = exp((double)lstep[p]);
      double ar = (double)Lre[p] * step, ai = (double)Lim[p] * step;
      double er = exp(ar);
      lam[p] = make_float2((float)(er * cos(ai)), (float)(er * sin(ai)));
      double ka = (double)CHUNK * ai, kr = exp((double)CHUNK * ar);
      lamK[p] = make_float2((float)(kr * cos(ka)), (float)(kr * sin(ka)));
    }
  }
}

// ---------------------------------------------------------------------------
// GEMM: out(M,N) = A(M,K) @ B(N,K)^T, bf16 in. 128x128 tile, BK=64, 4 waves,
// 4x4 mfma_f32_16x16x32_bf16. Grid (M/128, N/128), blockIdx.x fastest =>
// all N-tiles of an M-panel on the same XCD (A-panel fetched once per chip).
// LDS XOR swizzle (row&7) on the 8-elem column group kills the 16-way bank
// aliasing of the plain BK=64 layout.
// OUT=0: bf16 store. OUT=1: fp32 store, fused 2*acc + Dv[col]*bf2f(Ub).
// ---------------------------------------------------------------------------
template <int OUT>
__global__ void gemm_bt(const unsigned short* __restrict__ A,
                        const unsigned short* __restrict__ B,
                        void* __restrict__ Cout,
                        const unsigned short* __restrict__ Ub,
                        const float* __restrict__ Dv) {
  const int K = 1024, N = 1024;
  __shared__ unsigned short sA[128 * 64];
  __shared__ unsigned short sB[128 * 64];
  const int tid = threadIdx.x;
  const int wave = tid >> 6, lane = tid & 63;
  const int quad = lane >> 4, l16 = lane & 15;
  const int m0 = blockIdx.x * 128, n0 = blockIdx.y * 128;
  const int wm = (wave & 1) * 64, wn = (wave >> 1) * 64;

  f32x4 acc[4][4] = {};

  for (int kt = 0; kt < K; kt += 64) {
    __syncthreads();
#pragma unroll
    for (int r = 0; r < 4; ++r) {
      int s = r * 256 + tid;                   // LDS slot = staging index
      int row = s >> 3;
      int j8 = (s & 7) ^ (row & 7);            // swizzled global column-group
      const unsigned short* ga = A + (size_t)(m0 + row) * K + kt + j8 * 8;
      const unsigned short* gb = B + (size_t)(n0 + row) * K + kt + j8 * 8;
      __builtin_amdgcn_global_load_lds(
          (const __attribute__((address_space(1))) unsigned int*)ga,
          (__attribute__((address_space(3))) unsigned int*)(sA + (r * 256 + wave * 64) * 8),
          16, 0, 0);
      __builtin_amdgcn_global_load_lds(
          (const __attribute__((address_space(1))) unsigned int*)gb,
          (__attribute__((address_space(3))) unsigned int*)(sB + (r * 256 + wave * 64) * 8),
          16, 0, 0);
    }
    __syncthreads();

#pragma unroll
    for (int h = 0; h < 2; ++h) {
      bf16x8 af[4], bfr[4];
#pragma unroll
      for (int i = 0; i < 4; ++i) {
        int ra = wm + i * 16 + l16;
        af[i] = *(const bf16x8*)(sA + ra * 64 + (((h << 2) + quad) ^ (ra & 7)) * 8);
      }
#pragma unroll
      for (int j = 0; j < 4; ++j) {
        int rb = wn + j * 16 + l16;
        bfr[j] = *(const bf16x8*)(sB + rb * 64 + (((h << 2) + quad) ^ (rb & 7)) * 8);
      }
#pragma unroll
      for (int i = 0; i < 4; ++i)
#pragma unroll
        for (int j = 0; j < 4; ++j)
          acc[i][j] = __builtin_amdgcn_mfma_f32_16x16x32_bf16(af[i], bfr[j], acc[i][j], 0, 0, 0);
    }
  }

#pragma unroll
  for (int i = 0; i < 4; ++i) {
#pragma unroll
    for (int j = 0; j < 4; ++j) {
      int col = n0 + wn + j * 16 + l16;
#pragma unroll
      for (int r = 0; r < 4; ++r) {
        int row = m0 + wm + i * 16 + quad * 4 + r;
        size_t o = (size_t)row * N + col;
        float v = acc[i][j][r];
        if (OUT) {
          float u = bf2f(Ub[o]);
          ((float*)Cout)[o] = 2.0f * v + Dv[col] * u;
        } else {
          ((unsigned short*)Cout)[o] = f2bf(v);
        }
      }
    }
  }
}

// ---------------------------------------------------------------------------
// Scan pass A, LDS-staged: block = (chunk, half). Stage 64 rows x 1024 B of
// Bu into LDS with full-row-contiguous global_load_lds sweeps (spreads HBM
// channels like a copy kernel -- the previous per-thread 2048 B-stride walk
// channel-camped at 1.1 TB/s). Then scan columns out of LDS (bank = tid%32,
// constant in t, 2 lanes/bank = free) and write chunk sums.
// ---------------------------------------------------------------------------
__global__ __launch_bounds__(256) void k_scanA(const unsigned short* __restrict__ Bu,
                                               const float2* __restrict__ lam,
                                               float2* __restrict__ csum) {
  __shared__ unsigned int tile[CHUNK * 256];   // 64 KB
  const int bid = blockIdx.x;                  // NCH*2 blocks
  const int chunk = bid >> 1, half = bid & 1;
  const int tid = threadIdx.x, wave = tid >> 6, lane = tid & 63;
  const unsigned int* gbase =
      (const unsigned int*)(Bu + (size_t)chunk * CHUNK * N2P) + half * 256;
#pragma unroll
  for (int r = 0; r < 16; ++r) {
    int row = r * 4 + wave;
    __builtin_amdgcn_global_load_lds(
        (const __attribute__((address_space(1))) unsigned int*)
            (gbase + (size_t)row * (N2P / 2) + lane * 4),
        (__attribute__((address_space(3))) unsigned int*)(tile + row * 256),
        16, 0, 0);
  }
  __syncthreads();
  const int p = half * 256 + tid;
  const float2 l = lam[p];
  float xr = 0.f, xi = 0.f;
#pragma unroll 16
  for (int t = 0; t < CHUNK; ++t) {
    unsigned int v = tile[t * 256 + tid];
    float br = bf2f((unsigned short)(v & 0xffffu));
    float bi = bf2f((unsigned short)(v >> 16));
    float nr = fmaf(l.x, xr, fmaf(-l.y, xi, br));
    float ni = fmaf(l.x, xi, fmaf(l.y, xr, bi));
    xr = nr; xi = ni;
  }
  csum[(size_t)chunk * P_DIM + p] = make_float2(xr, xi);
}

// ---------------------------------------------------------------------------
// Scan pass C, LDS-staged, with Horner lookback over csum (L2-resident, loads
// independent). Stages Bu tile, scans seeded with the carry, overwrites the
// tile in place with packed bf16 xs, then wide dwordx4 store phase.
// ---------------------------------------------------------------------------
__global__ __launch_bounds__(256) void k_scanC(const unsigned short* __restrict__ Bu,
                                               const float2* __restrict__ lam,
                                               const float2* __restrict__ lamK,
                                               const float2* __restrict__ csum,
                                               unsigned short* __restrict__ xs) {
  __shared__ unsigned int tile[CHUNK * 256];   // 64 KB
  const int bid = blockIdx.x;
  const int chunk = bid >> 1, half = bid & 1;
  const int tid = threadIdx.x, wave = tid >> 6, lane = tid & 63;
  const unsigned int* gbase =
      (const unsigned int*)(Bu + (size_t)chunk * CHUNK * N2P) + half * 256;
#pragma unroll
  for (int r = 0; r < 16; ++r) {
    int row = r * 4 + wave;
    __builtin_amdgcn_global_load_lds(
        (const __attribute__((address_space(1))) unsigned int*)
            (gbase + (size_t)row * (N2P / 2) + lane * 4),
        (__attribute__((address_space(3))) unsigned int*)(tile + row * 256),
        16, 0, 0);
  }
  // lookback while the DMA is in flight
  const int p = half * 256 + tid;
  const float2 l = lam[p];
  const float2 lk = lamK[p];
  float cr = 0.f, ci = 0.f;
#pragma unroll 4
  for (int j = 0; j < chunk; ++j) {
    float2 s = csum[(size_t)j * P_DIM + p];
    float nr = fmaf(lk.x, cr, fmaf(-lk.y, ci, s.x));
    float ni = fmaf(lk.x, ci, fmaf(lk.y, cr, s.y));
    cr = nr; ci = ni;
  }
  __syncthreads();
  float xr = cr, xi = ci;
#pragma unroll 16
  for (int t = 0; t < CHUNK; ++t) {
    unsigned int v = tile[t * 256 + tid];
    float br = bf2f((unsigned short)(v & 0xffffu));
    float bi = bf2f((unsigned short)(v >> 16));
    float nr = fmaf(l.x, xr, fmaf(-l.y, xi, br));
    float ni = fmaf(l.x, xi, fmaf(l.y, xr, bi));
    xr = nr; xi = ni;
    tile[t * 256 + tid] = (unsigned int)f2bf(xr) | ((unsigned int)f2bf(xi) << 16);
  }
  __syncthreads();
  unsigned int* obase = (unsigned int*)(xs + (size_t)chunk * CHUNK * N2P) + half * 256;
#pragma unroll
  for (int r = 0; r < 16; ++r) {
    int row = r * 4 + wave;
    *(u32x4*)(obase + (size_t)row * (N2P / 2) + lane * 4) =
        *(const u32x4*)(tile + row * 256 + lane * 4);
  }
}

// ---------------------------------------------------------------------------
extern "C" void kernel_launch(void* const* d_in, const int* in_sizes, int n_in,
                              void* d_out, int out_size, void* d_ws, size_t ws_size,
                              hipStream_t stream) {
  const float* U    = (const float*)d_in[0];
  const float* Lre  = (const float*)d_in[1];
  const float* Lim  = (const float*)d_in[2];
  const float* Bre  = (const float*)d_in[3];
  const float* Bim  = (const float*)d_in[4];
  const float* Cre  = (const float*)d_in[5];
  const float* Cim  = (const float*)d_in[6];
  const float* Dv   = (const float*)d_in[7];
  const float* lstp = (const float*)d_in[8];
  float* out = (float*)d_out;

  size_t off = 0;
  char* ws = (char*)d_ws;
  auto give = [&](size_t bytes) -> void* {
    void* p = ws + off;
    off += (bytes + 255) & ~(size_t)255;
    return p;
  };

  unsigned short* ubf  = (unsigned short*)give((size_t)L_SEQ * H_DIM * 2);  // 33.5 MB
  unsigned short* Bp   = (unsigned short*)give((size_t)N2P * H_DIM * 2);    //  2 MB
  unsigned short* Cp   = (unsigned short*)give((size_t)H_DIM * N2P * 2);    //  2 MB
  unsigned short* Bu   = (unsigned short*)give((size_t)L_SEQ * N2P * 2);    // 33.5 MB
  unsigned short* xs   = (unsigned short*)give((size_t)L_SEQ * N2P * 2);    // 33.5 MB
  float2*         lam  = (float2*)give(P_DIM * sizeof(float2));
  float2*         lamK = (float2*)give(P_DIM * sizeof(float2));
  float2*         csum = (float2*)give((size_t)NCH * P_DIM * sizeof(float2));

  k_pack_all<<<NB_U + NB_B + NB_C + NB_T, 256, 0, stream>>>(
      U, ubf, Bre, Bim, Bp, Cre, Cim, Cp, Lre, Lim, lstp, lam, lamK);

  gemm_bt<0><<<dim3(L_SEQ / 128, N2P / 128), 256, 0, stream>>>(ubf, Bp, Bu, nullptr, nullptr);

  k_scanA<<<NCH * 2, 256, 0, stream>>>(Bu, lam, csum);
  k_scanC<<<NCH * 2, 256, 0, stream>>>(Bu, lam, lamK, csum, xs);

  gemm_bt<1><<<dim3(L_SEQ / 128, N2P / 128), 256, 0, stream>>>(xs, Cp, out, ubf, Dv);
}